// Round 12
// baseline (17.981 us; speedup 1.0000x reference)
//
#include <hip/hip_runtime.h>

// PairwiseRankingLoss: B=128 rows, L=1024.
// loss = sum_{b, pos i, neg j} relu(1 - s[b,i] + s[b,j]) / max(num_pairs, 1)
//
// MEASUREMENT ROUND: exact R10 structure (best-band kernel), but K1 is
// launched TWICE. K1 is idempotent (pure function of inputs -> same partials),
// so correctness is unchanged; the marginal dur_us vs R10 directly measures
// K1's true duration + one node overhead, discriminating:
//   World A: K1 ~8 us (internal stalls remain)  -> total ~20-21 us
//   World B: K1 ~2-3 us (launch-overhead floor) -> total ~14-15 us

#define PRL_B 128
#define PRL_L 1024
#define SPLIT 8
#define NBLK  (PRL_B * SPLIT)   // 1024 blocks
#define GSTAT 18                // static float4-groups per slice

// Hot loop specialized on K = pos values per thread (block-uniform runtime).
// Static GSTAT-group main body + (normally empty) dynamic tail.
template<int K>
__device__ __forceinline__ float hotloop(const float4* __restrict__ d4,
                                         int c0, int t0, int t1, float4 pv) {
    float acc[K];
#pragma unroll
    for (int k = 0; k < K; ++k) acc[k] = 0.f;
#pragma unroll
    for (int c = 0; c < GSTAT; ++c) {
        const float4 d = d4[c0 + c];   // wave-uniform LDS broadcast, static ofs
#pragma unroll
        for (int k = 0; k < K; ++k) {
            const float pk = (k == 0) ? pv.x : (k == 1) ? pv.y : (k == 2) ? pv.z : pv.w;
            acc[k] += (fmaxf(d.x - pk, 0.f) + fmaxf(d.y - pk, 0.f))
                    + (fmaxf(d.z - pk, 0.f) + fmaxf(d.w - pk, 0.f));
        }
    }
    for (int c = t0; c < t1; ++c) {    // tail: only if nn > 4*SPLIT*GSTAT
        const float4 d = d4[c];
#pragma unroll
        for (int k = 0; k < K; ++k) {
            const float pk = (k == 0) ? pv.x : (k == 1) ? pv.y : (k == 2) ? pv.z : pv.w;
            acc[k] += (fmaxf(d.x - pk, 0.f) + fmaxf(d.y - pk, 0.f))
                    + (fmaxf(d.z - pk, 0.f) + fmaxf(d.w - pk, 0.f));
        }
    }
    float r = 0.f;
#pragma unroll
    for (int k = 0; k < K; ++k) r += acc[k];
    return r;
}

__global__ __launch_bounds__(256, 4) void prl_partial(
    const float* __restrict__ y_pred,
    const int*   __restrict__ y_true,
    float* __restrict__ bsum,    // [NBLK]
    int*   __restrict__ bpairs)  // [NBLK]
{
    __shared__ float4 s_pos4[PRL_L / 4];   // compacted pos scores (+3e38 pad)
    __shared__ float4 s_neg4[PRL_L / 4];   // compacted 1+neg scores (-3e38 pad)
    __shared__ int    s_cntP[4];
    __shared__ float  s_wsum[4];
    float* s_pos = (float*)s_pos4;
    float* s_neg = (float*)s_neg4;

    const int blk  = blockIdx.x;
    const int b    = blk >> 3;            // / SPLIT
    const int s    = blk & (SPLIT - 1);
    const int t    = threadIdx.x;
    const int lane = t & 63;
    const int w    = t >> 6;

    // Vectorized staging: one float4 + one int4 per thread covers the row.
    const float4 sc = ((const float4*)(y_pred + (size_t)b * PRL_L))[t];
    const int4   lv = ((const int4*)  (y_true + (size_t)b * PRL_L))[t];
    const float sv[4] = {sc.x, sc.y, sc.z, sc.w};
    const int   lb[4] = {lv.x, lv.y, lv.z, lv.w};

    // Pass 1: per-wave pos masks via ballot; labels in {0,1} => neg = ~pos.
    unsigned long long mP[4];
    int cP = 0;
#pragma unroll
    for (int r = 0; r < 4; ++r) {
        mP[r] = __ballot(lb[r] == 1);
        cP += (int)__popcll(mP[r]);
    }
    if (lane == 0) s_cntP[w] = cP;

    // Sentinel-init (pad regions survive; valid regions overwritten below).
    s_pos4[t] = make_float4( 3.0e38f,  3.0e38f,  3.0e38f,  3.0e38f);
    s_neg4[t] = make_float4(-3.0e38f, -3.0e38f, -3.0e38f, -3.0e38f);
    __syncthreads();

    // Wave offsets + row totals (np; nn = L - np).
    int offP = 0, np = 0;
#pragma unroll
    for (int ww = 0; ww < 4; ++ww) {
        const int p_ = s_cntP[ww];
        np += p_;
        if (ww < w) offP += p_;
    }
    const int nn   = PRL_L - np;
    const int offN = 256 * w - offP;

    // Pass 2: scatter compacted values (order irrelevant).
    const unsigned long long lt = (1ULL << lane) - 1ULL;
    int bP = offP, bN = offN;
#pragma unroll
    for (int r = 0; r < 4; ++r) {
        const unsigned long long mp = mP[r], mn = ~mp;
        if (lb[r] == 1) s_pos[bP + (int)__popcll(mp & lt)] = sv[r];
        else            s_neg[bN + (int)__popcll(mn & lt)] = 1.0f + sv[r];
        bP += (int)__popcll(mp);
        bN += 64 - (int)__popcll(mp);
    }
    __syncthreads();

    // This thread's pos values (sentinel-padded reads are safe).
    const float4 pv = make_float4(s_pos[t], s_pos[t + 256],
                                  s_pos[t + 512], s_pos[t + 768]);
    const int KP  = (np + 255) >> 8;              // 0..4, block-uniform
    const int NN4 = (nn + 3) >> 2;                // float4 groups of negs

    // Static slice [s*GSTAT, s*GSTAT+GSTAT); sentinels past NN4 contribute 0.
    const int c0 = s * GSTAT;                     // max 144 <= 256
    int t0 = 0, t1 = 0;
    if (s == SPLIT - 1 && NN4 > SPLIT * GSTAT) {  // nn > 576: rare tail
        t0 = SPLIT * GSTAT;
        t1 = NN4;
    }

    float local;
    const float4* neg4 = (const float4*)s_neg4;
    switch (KP) {
        case 0:  local = 0.f; break;
        case 1:  local = hotloop<1>(neg4, c0, t0, t1, pv); break;
        case 2:  local = hotloop<2>(neg4, c0, t0, t1, pv); break;
        case 3:  local = hotloop<3>(neg4, c0, t0, t1, pv); break;
        default: local = hotloop<4>(neg4, c0, t0, t1, pv); break;
    }

    // Block reduction (sum only; pair count is uniform, no reduce needed).
#pragma unroll
    for (int off = 32; off >= 1; off >>= 1)
        local += __shfl_down(local, off, 64);
    if (lane == 0) s_wsum[w] = local;
    __syncthreads();

    if (t == 0) {
        bsum[blk]   = (s_wsum[0] + s_wsum[1]) + (s_wsum[2] + s_wsum[3]);
        bpairs[blk] = (s == 0) ? np * nn : 0;   // exact pair count, once/row
    }
}

// Single-wave finalize: 64 threads read all 1024 partials (8 KB).
__global__ __launch_bounds__(64) void prl_finalize(
    const float* __restrict__ bsum,
    const int*   __restrict__ bpairs,
    float* __restrict__ out)
{
    const int t = threadIdx.x;
    const float4* s4 = (const float4*)bsum;
    const int4*   p4 = (const int4*)bpairs;

    float fs = 0.f; int ps = 0;
#pragma unroll
    for (int k = 0; k < 4; ++k) {           // 4 x 64 float4 = 1024 partials
        const float4 a = s4[t + 64 * k];
        const int4  ia = p4[t + 64 * k];
        fs += (a.x + a.y) + (a.z + a.w);
        ps += (ia.x + ia.y) + (ia.z + ia.w);
    }
#pragma unroll
    for (int off = 32; off >= 1; off >>= 1) {
        fs += __shfl_down(fs, off, 64);
        ps += __shfl_down(ps, off, 64);
    }
    if (t == 0)
        out[0] = (ps > 0) ? (fs / fmaxf((float)ps, 1.0f)) : fs;
}

extern "C" void kernel_launch(void* const* d_in, const int* in_sizes, int n_in,
                              void* d_out, int out_size, void* d_ws, size_t ws_size,
                              hipStream_t stream) {
    const float* y_pred = (const float*)d_in[0];
    const int*   y_true = (const int*)d_in[1];
    float* out = (float*)d_out;

    // ws layout: float bsum[NBLK]; int bpairs[NBLK]
    float* bsum   = (float*)d_ws;
    int*   bpairs = (int*)((char*)d_ws + NBLK * sizeof(float));

    // K1 launched TWICE (idempotent): marginal cost of the 2nd node = K1's
    // true duration + node overhead. Deterministic: same writes both times.
    prl_partial<<<NBLK, 256, 0, stream>>>(y_pred, y_true, bsum, bpairs);
    prl_partial<<<NBLK, 256, 0, stream>>>(y_pred, y_true, bsum, bpairs);
    prl_finalize<<<1, 64, 0, stream>>>(bsum, bpairs, out);
}